// Round 1
// 494.947 us; speedup vs baseline: 1.0758x; 1.0758x over previous
//
#include <hip/hip_runtime.h>

typedef unsigned char  u8;
typedef unsigned short u16;
typedef unsigned int   u32;

#define NN   16384     // nodes
#define EE   262144    // edges
#define RR   9         // relations
#define DIN  384
#define DH   768
#define KSU  3456      // RR*DIN
#define KS   3488      // KSU + 9 cnt cols + pad to 32
#define NPB  8         // nodes per block in phase2
#define PCOP 16        // partial pooled copies

typedef float  f32x4 __attribute__((ext_vector_type(4)));
typedef float  f32x2 __attribute__((ext_vector_type(2)));
typedef __bf16 b16x8 __attribute__((ext_vector_type(8)));

__device__ __forceinline__ u16 f2bf(float f){
  u32 u = __builtin_bit_cast(u32, f);
  u += 0x7fffu + ((u >> 16) & 1u);          // RNE
  return (u16)(u >> 16);
}
__device__ __forceinline__ float bf2f(u16 h){
  u32 u = ((u32)h) << 16;
  return __builtin_bit_cast(float, u);
}
// async global->LDS, 16B per lane; LDS dest = wave-uniform base + lane*16
__device__ __forceinline__ void gll16(const void* g, void* l){
  __builtin_amdgcn_global_load_lds((const __attribute__((address_space(1))) void*)g,
                                   (__attribute__((address_space(3))) void*)l, 16, 0, 0);
}

// ---------------- CSR build ----------------
__global__ void k_count(const int* __restrict__ dst, int* __restrict__ counts){
  const int e = blockIdx.x*256 + threadIdx.x;
  if (e < EE) atomicAdd(&counts[dst[e]], 1);
}

__global__ __launch_bounds__(1024) void k_scan(const int* __restrict__ counts,
                                               int* __restrict__ starts,
                                               int* __restrict__ cursor){
  __shared__ int tot[1024];
  const int t = threadIdx.x;
  int loc[16]; int s = 0;
  #pragma unroll
  for (int j=0;j<16;j++){ loc[j] = counts[t*16+j]; s += loc[j]; }
  tot[t] = s;
  __syncthreads();
  for (int o=1;o<1024;o<<=1){
    int v = (t>=o) ? tot[t-o] : 0;
    __syncthreads();
    tot[t] += v;
    __syncthreads();
  }
  int run = tot[t] - s;  // exclusive prefix
  #pragma unroll
  for (int j=0;j<16;j++){ starts[t*16+j] = run; cursor[t*16+j] = run; run += loc[j]; }
  if (t == 1023) starts[NN] = run;
}

// scatter edges into CSR order; emit pre-gathered src/rtype arrays
__global__ void k_place(const int* __restrict__ src, const int* __restrict__ dst,
                        const int* __restrict__ et, int* __restrict__ cursor,
                        int* __restrict__ srcp, int* __restrict__ rp){
  const int e = blockIdx.x*256 + threadIdx.x;
  if (e < EE){
    const int p = atomicAdd(&cursor[dst[e]], 1);
    srcp[p] = src[e];
    rp[p]   = et[e];
  }
}

// ---------------- weight conversion to bf16 ----------------
__global__ void k_convW1(const float* __restrict__ rW, const float* __restrict__ rb,
                         u16* __restrict__ Wst){
  const int hh = blockIdx.y;
  const int k  = blockIdx.x*256 + threadIdx.x;
  if (k >= KS) return;
  float v;
  if (k < KSU){ const int r = k / DIN; const int d = k - r*DIN;
                v = rW[((long)r*DH + hh)*DIN + d]; }
  else if (k < KSU + RR){ const int r = k - KSU; v = rb[(long)r*DH + hh]; }
  else v = 0.f;
  Wst[(long)hh*KS + k] = f2bf(v);
}

__global__ void k_convW2(const float* __restrict__ lW, const float* __restrict__ sW,
                         u16* __restrict__ WB){
  const int idx = blockIdx.x*256 + threadIdx.x;  // exactly 1179648 threads
  const float v = (idx < DH*DH) ? lW[idx] : sW[idx - DH*DH];
  WB[idx] = f2bf(v);
}

// ---------------- phase1 fused: one wave per dst node, VGPR accumulators ----
// s[i, r*384+d] = sum_{p in seg(i)} (dot(x[i],x[srcp])/nc[r]) * x[srcp, d]
// s[i, 3456+r]  = sum norm ; rest of row = 0
// 4 waves/block (4 nodes), 2-edge ILP to halve the shfl-chain latency per edge.
__global__ __launch_bounds__(256, 3) void k_phase1f(const float* __restrict__ x,
                                                    const int* __restrict__ srcp,
                                                    const int* __restrict__ rp,
                                                    const float* __restrict__ nc,
                                                    const int* __restrict__ starts,
                                                    u16* __restrict__ s){
  const int wv = threadIdx.x >> 6;
  const int l  = threadIdx.x & 63;
  const int i  = blockIdx.x*4 + wv;
  const float* xdp = x + (long)i*DIN;
  const f32x2 xd0 = *(const f32x2*)(xdp + 2*l);
  const f32x2 xd1 = *(const f32x2*)(xdp + 128 + 2*l);
  const f32x2 xd2 = *(const f32x2*)(xdp + 256 + 2*l);
  float acc[RR][6];
  float cacc[RR];
  #pragma unroll
  for (int r=0;r<RR;r++){
    cacc[r] = 0.f;
    #pragma unroll
    for (int j=0;j<6;j++) acc[r][j] = 0.f;
  }
  const int e0 = starts[i], e1 = starts[i+1];
  f32x2 A0={0.f,0.f}, A1={0.f,0.f}, A2={0.f,0.f};
  f32x2 B0={0.f,0.f}, B1={0.f,0.f}, B2={0.f,0.f};
  int rA = 0, rB = 0;
  if (e0 < e1){
    const float* xs = x + (long)srcp[e0]*DIN;
    A0 = *(const f32x2*)(xs + 2*l);
    A1 = *(const f32x2*)(xs + 128 + 2*l);
    A2 = *(const f32x2*)(xs + 256 + 2*l);
    rA = rp[e0];
  }
  if (e0+1 < e1){
    const float* xs = x + (long)srcp[e0+1]*DIN;
    B0 = *(const f32x2*)(xs + 2*l);
    B1 = *(const f32x2*)(xs + 128 + 2*l);
    B2 = *(const f32x2*)(xs + 256 + 2*l);
    rB = rp[e0+1];
  }
  for (int p=e0; p<e1; p+=2){
    const f32x2 a0=A0, a1=A1, a2=A2;
    const f32x2 b0=B0, b1=B1, b2=B2;
    const int ra = rA, rb = rB;
    const bool hb = (p+1 < e1);
    if (p+2 < e1){                        // prefetch next pair
      const float* xs = x + (long)srcp[p+2]*DIN;
      A0 = *(const f32x2*)(xs + 2*l);
      A1 = *(const f32x2*)(xs + 128 + 2*l);
      A2 = *(const f32x2*)(xs + 256 + 2*l);
      rA = rp[p+2];
    }
    if (p+3 < e1){
      const float* xs = x + (long)srcp[p+3]*DIN;
      B0 = *(const f32x2*)(xs + 2*l);
      B1 = *(const f32x2*)(xs + 128 + 2*l);
      B2 = *(const f32x2*)(xs + 256 + 2*l);
      rB = rp[p+3];
    }
    float pa = xd0.x*a0.x + xd0.y*a0.y + xd1.x*a1.x + xd1.y*a1.y
             + xd2.x*a2.x + xd2.y*a2.y;
    float pb = xd0.x*b0.x + xd0.y*b0.y + xd1.x*b1.x + xd1.y*b1.y
             + xd2.x*b2.x + xd2.y*b2.y;
    #pragma unroll
    for (int o=32;o;o>>=1){                // two interleaved butterflies (ILP)
      pa += __shfl_xor(pa, o);
      pb += __shfl_xor(pb, o);
    }
    // 1/nc[r] factored out of the loop (applied once at writeout)
    #define UPD(R,P,c0,c1,c2) { cacc[R] += P; \
      acc[R][0] += P*c0.x; acc[R][1] += P*c0.y; acc[R][2] += P*c1.x; \
      acc[R][3] += P*c1.y; acc[R][4] += P*c2.x; acc[R][5] += P*c2.y; }
    switch (ra){                           // wave-uniform branch
      case 0: UPD(0,pa,a0,a1,a2); break; case 1: UPD(1,pa,a0,a1,a2); break;
      case 2: UPD(2,pa,a0,a1,a2); break; case 3: UPD(3,pa,a0,a1,a2); break;
      case 4: UPD(4,pa,a0,a1,a2); break; case 5: UPD(5,pa,a0,a1,a2); break;
      case 6: UPD(6,pa,a0,a1,a2); break; case 7: UPD(7,pa,a0,a1,a2); break;
      default: UPD(8,pa,a0,a1,a2); break;
    }
    if (hb){
      switch (rb){
        case 0: UPD(0,pb,b0,b1,b2); break; case 1: UPD(1,pb,b0,b1,b2); break;
        case 2: UPD(2,pb,b0,b1,b2); break; case 3: UPD(3,pb,b0,b1,b2); break;
        case 4: UPD(4,pb,b0,b1,b2); break; case 5: UPD(5,pb,b0,b1,b2); break;
        case 6: UPD(6,pb,b0,b1,b2); break; case 7: UPD(7,pb,b0,b1,b2); break;
        default: UPD(8,pb,b0,b1,b2); break;
      }
    }
    #undef UPD
  }
  u16* srow = s + (long)i*KS;
  #pragma unroll
  for (int r=0;r<RR;r++){
    const float inv = 1.0f / nc[r];
    #pragma unroll
    for (int seg=0;seg<3;seg++){
      const u32 pk = (u32)f2bf(acc[r][seg*2]*inv)
                   | ((u32)f2bf(acc[r][seg*2+1]*inv) << 16);
      ((u32*)(srow + r*DIN + seg*128))[l] = pk;   // cols seg*128 + {2l, 2l+1}
    }
  }
  float cv = 0.f;
  #pragma unroll
  for (int r=0;r<RR;r++) cv = (l == r) ? cacc[r] : cv;
  if (l < 32){
    const float invl = (l < RR) ? 1.0f/nc[l] : 0.f;
    srow[KSU + l] = f2bf(l < RR ? cv*invl : 0.f);
  }
}

// ---------------- m97-style bf16 GEMM: C = A * B^T (both K-major) ----------------
// grid: x = M-tile (fast), y = N-tile  -> same-A blocks land on same XCD (id%8)
// MODE 0: O0 = relu(C) bf16, stride DH           (gemm1: x1)
// MODE 1: n<768 -> O0 = C+b0[n]; else O1 = C+b1  (gemm2: hm / selfx)
template<int MODE>
__global__ __launch_bounds__(256, 2)
void k_gemm_bt(const u16* __restrict__ A, const u16* __restrict__ B,
               int M, int N, int K,
               u16* __restrict__ O0, u16* __restrict__ O1,
               const float* __restrict__ b0, const float* __restrict__ b1)
{
  __shared__ __align__(16) u16 As[128*32];
  __shared__ __align__(16) u16 Bs[128*32];
  const int t  = threadIdx.x;
  const int wv = t >> 6;
  const int ln = t & 63;
  const int wm = wv >> 1, wn = wv & 1;
  const long m0 = (long)blockIdx.x * 128;
  const long n0 = (long)blockIdx.y * 128;

  const int srow  = ln >> 2;         // staging: lane -> row within 16-row segment
  const int skcol = (ln & 3) * 8;    // k element offset (8 bf16 = 16B)

  f32x4 acc[4][4];
  #pragma unroll
  for (int i=0;i<4;i++)
    #pragma unroll
    for (int j=0;j<4;j++) acc[i][j] = {0.f,0.f,0.f,0.f};

  const int fr = ln & 15, fq = ln >> 4;
  const int nk = K >> 5;
  for (int kb=0; kb<nk; ++kb){
    const long k0 = (long)kb * 32;
    #pragma unroll
    for (int q=0;q<2;q++){
      const int seg = wv*2 + q;
      const int row = seg*16 + srow;
      gll16(A + (m0 + row)*(long)K + k0 + skcol, &As[seg*512]);
      gll16(B + (n0 + row)*(long)K + k0 + skcol, &Bs[seg*512]);
    }
    __syncthreads();
    b16x8 av[4], bv[4];
    #pragma unroll
    for (int i=0;i<4;i++){
      av[i] = *(const b16x8*)&As[(wm*64 + i*16 + fr)*32 + fq*8];
      bv[i] = *(const b16x8*)&Bs[(wn*64 + i*16 + fr)*32 + fq*8];
    }
    #pragma unroll
    for (int i=0;i<4;i++)
      #pragma unroll
      for (int j=0;j<4;j++)
        acc[i][j] = __builtin_amdgcn_mfma_f32_16x16x32_bf16(av[i], bv[j], acc[i][j], 0, 0, 0);
    __syncthreads();
  }

  #pragma unroll
  for (int i=0;i<4;i++){
    #pragma unroll
    for (int j=0;j<4;j++){
      #pragma unroll
      for (int r=0;r<4;r++){
        const long m = m0 + wm*64 + i*16 + fq*4 + r;   // C row = quad*4+reg
        const long n = n0 + wn*64 + j*16 + fr;         // C col = lane&15
        float v = acc[i][j][r];
        if (MODE == 0){
          v = v > 0.f ? v : 0.f;
          O0[m*DH + n] = f2bf(v);
        } else {
          if (n < DH) O0[m*DH + n]      = f2bf(v + b0[n]);
          else        O1[m*DH + (n-DH)] = f2bf(v + b1[n-DH]);
        }
      }
    }
  }
}

// ---------------- phase2 fused with mean-pool: aggr2 + self + relu -> pooled ----
// Each block walks NPB nodes' CSR segments as one flat, software-pipelined edge
// stream. x2 is never materialized; per-thread pool registers are flushed with
// 6 atomicAdds into one of PCOP partial-pool copies.
// lane t owns cols {2t,2t+1} of each 256-col third (dword-coalesced bf16 loads).
__global__ __launch_bounds__(128) void k_phase2(const u16* __restrict__ hm,
                                                const u16* __restrict__ sfx,
                                                const int* __restrict__ srcp,
                                                const int* __restrict__ starts,
                                                float* __restrict__ pooledP){
  const int t  = threadIdx.x;
  const int i0 = blockIdx.x * NPB;
  int p = starts[i0];
  const int pend = starts[i0 + NPB];
  u32 C0=0u, C1=0u, C2=0u;
  if (p < pend){
    const u32* hr = (const u32*)(hm + (long)srcp[p]*DH);
    C0 = hr[t]; C1 = hr[t+128]; C2 = hr[t+256];
  }
  float pool[6] = {0.f,0.f,0.f,0.f,0.f,0.f};
  for (int i=i0; i<i0+NPB; ++i){
    const int e1 = starts[i+1];
    float a[6] = {0.f,0.f,0.f,0.f,0.f,0.f};
    while (p < e1){
      const u32 d0=C0, d1=C1, d2=C2;
      if (p+1 < pend){                     // prefetch across node boundaries
        const u32* hr = (const u32*)(hm + (long)srcp[p+1]*DH);
        C0 = hr[t]; C1 = hr[t+128]; C2 = hr[t+256];
      }
      a[0] += bf2f((u16)d0); a[1] += bf2f((u16)(d0>>16));
      a[2] += bf2f((u16)d1); a[3] += bf2f((u16)(d1>>16));
      a[4] += bf2f((u16)d2); a[5] += bf2f((u16)(d2>>16));
      ++p;
    }
    const u32* sr = (const u32*)(sfx + (long)i*DH);
    const u32 s0 = sr[t], s1 = sr[t+128], s2 = sr[t+256];
    float v;
    v = a[0] + bf2f((u16)s0);        pool[0] += v > 0.f ? v : 0.f;
    v = a[1] + bf2f((u16)(s0>>16));  pool[1] += v > 0.f ? v : 0.f;
    v = a[2] + bf2f((u16)s1);        pool[2] += v > 0.f ? v : 0.f;
    v = a[3] + bf2f((u16)(s1>>16));  pool[3] += v > 0.f ? v : 0.f;
    v = a[4] + bf2f((u16)s2);        pool[4] += v > 0.f ? v : 0.f;
    v = a[5] + bf2f((u16)(s2>>16));  pool[5] += v > 0.f ? v : 0.f;
  }
  float* pd = pooledP + (blockIdx.x & (PCOP-1)) * DH;
  atomicAdd(&pd[2*t],       pool[0]);
  atomicAdd(&pd[2*t+1],     pool[1]);
  atomicAdd(&pd[256+2*t],   pool[2]);
  atomicAdd(&pd[256+2*t+1], pool[3]);
  atomicAdd(&pd[512+2*t],   pool[4]);
  atomicAdd(&pd[512+2*t+1], pool[5]);
}

__global__ __launch_bounds__(256) void k_final(const float* __restrict__ pooledP,
                                               const float* __restrict__ oW,
                                               const float* __restrict__ ob,
                                               float* __restrict__ out){
  __shared__ float ps[DH];
  __shared__ float red[256];
  const int t = threadIdx.x;
  for (int h=t; h<DH; h+=256){
    float s = 0.f;
    #pragma unroll
    for (int c=0;c<PCOP;c++) s += pooledP[c*DH + h];
    ps[h] = s;
  }
  __syncthreads();
  for (int c=0;c<5;c++){
    float p = 0.f;
    for (int h=t; h<DH; h+=256) p += ps[h]*oW[c*DH + h];
    red[t] = p; __syncthreads();
    for (int o=128;o;o>>=1){ if (t<o) red[t]+=red[t+o]; __syncthreads(); }
    if (t == 0) out[c] = red[0]*(1.f/(float)NN) + ob[c];
    __syncthreads();
  }
}

// ---------------- launch ----------------
extern "C" void kernel_launch(void* const* d_in, const int* in_sizes, int n_in,
                              void* d_out, int out_size, void* d_ws, size_t ws_size,
                              hipStream_t stream)
{
  (void)in_sizes; (void)n_in; (void)out_size; (void)ws_size;
  const float* x     = (const float*)d_in[0];
  const int*   ei    = (const int*)  d_in[1];   // [2][E]: row0=src, row1=dst
  const int*   et    = (const int*)  d_in[2];
  const float* relW  = (const float*)d_in[3];
  const float* relb  = (const float*)d_in[4];
  const float* nc    = (const float*)d_in[5];
  const float* linW  = (const float*)d_in[6];
  const float* linb  = (const float*)d_in[7];
  const float* selfW = (const float*)d_in[8];
  const float* selfb = (const float*)d_in[9];
  const float* outW  = (const float*)d_in[10];
  const float* outb  = (const float*)d_in[11];
  float* out = (float*)d_out;

  // workspace layout (256B aligned); hm/selfx alias S (dead after gemm1)
  u8* w = (u8*)d_ws;
  int*   counts = (int*)(w + 0);              // 64 KB
  int*   starts = (int*)(w + 65536);          // 16385*4
  int*   cursor = (int*)(w + 131328);         // 64 KB
  int*   srcp   = (int*)(w + 196864);         // 1 MB
  int*   rp     = (int*)(w + 2294016);        // 1 MB
  u16*   Wst    = (u16*)(w + 4391168);        // 768*3488*2  = 5.36 MB
  u16*   WB     = (u16*)(w + 9748736);        // 1536*768*2  = 2.36 MB
  u16*   x1     = (u16*)(w + 12108032);       // 16384*768*2 = 25.2 MB
  u16*   S      = (u16*)(w + 37276928);       // 16384*3488*2 = 114.3 MB
  u16*   hm     = S;                          // alias: 25.2 MB
  u16*   sfx    = (u16*)(w + 37276928 + 25165824);
  // partial pooled copies live in S's tail (dead after gemm1 reads S)
  float* pooledP = (float*)(w + 37276928 + 50331648);  // PCOP*768*4 = 48 KB

  const int* esrc = ei;
  const int* edst = ei + EE;

  hipMemsetAsync(counts, 0, NN*sizeof(int), stream);

  k_count <<<EE/256, 256, 0, stream>>>(edst, counts);
  k_scan  <<<1, 1024, 0, stream>>>(counts, starts, cursor);
  k_place <<<EE/256, 256, 0, stream>>>(esrc, edst, et, cursor, srcp, rp);
  k_convW1<<<dim3(14, DH), 256, 0, stream>>>(relW, relb, Wst);
  k_convW2<<<(2*DH*DH)/256, 256, 0, stream>>>(linW, selfW, WB);
  k_phase1f<<<NN/4, 256, 0, stream>>>(x, srcp, rp, nc, starts, S);
  k_gemm_bt<0><<<dim3(NN/128, DH/128), 256, 0, stream>>>(
      S, Wst, NN, DH, KS, x1, (u16*)nullptr, (const float*)nullptr, (const float*)nullptr);
  // S fully consumed by gemm1; its tail is now free for the pooled partials
  hipMemsetAsync(pooledP, 0, PCOP*DH*sizeof(float), stream);
  k_gemm_bt<1><<<dim3(NN/128, 2*DH/128), 256, 0, stream>>>(
      x1, WB, NN, 2*DH, DH, hm, sfx, linb, selfb);
  k_phase2<<<NN/NPB, 128, 0, stream>>>(hm, sfx, srcp, starts, pooledP);
  k_final <<<1, 256, 0, stream>>>(pooledP, outW, outb, out);
}

// Round 2
// 476.795 us; speedup vs baseline: 1.1167x; 1.0381x over previous
//
#include <hip/hip_runtime.h>

typedef unsigned char  u8;
typedef unsigned short u16;
typedef unsigned int   u32;

#define NN   16384     // nodes
#define EE   262144    // edges
#define RR   9         // relations
#define DIN  384
#define DH   768
#define KSU  3456      // RR*DIN
#define KS   3488      // KSU + 9 cnt cols + pad to 32
#define NPB  4         // nodes per block in phase2
#define PCOP 16        // partial pooled copies

typedef float  f32x4 __attribute__((ext_vector_type(4)));
typedef float  f32x2 __attribute__((ext_vector_type(2)));
typedef __bf16 b16x8 __attribute__((ext_vector_type(8)));

__device__ __forceinline__ u16 f2bf(float f){
  u32 u = __builtin_bit_cast(u32, f);
  u += 0x7fffu + ((u >> 16) & 1u);          // RNE
  return (u16)(u >> 16);
}
__device__ __forceinline__ float bf2f(u16 h){
  u32 u = ((u32)h) << 16;
  return __builtin_bit_cast(float, u);
}
// async global->LDS, 16B per lane; LDS dest = wave-uniform base + lane*16
__device__ __forceinline__ void gll16(const void* g, void* l){
  __builtin_amdgcn_global_load_lds((const __attribute__((address_space(1))) void*)g,
                                   (__attribute__((address_space(3))) void*)l, 16, 0, 0);
}
// DPP row rotate (16-lane rows), full-rate VALU — no LDS pipe
template<int N> __device__ __forceinline__ float dppror(float v){
  return __builtin_bit_cast(float,
    __builtin_amdgcn_update_dpp(0, __builtin_bit_cast(int, v), 0x120+N, 0xF, 0xF, true));
}
__device__ __forceinline__ float swz16(float v){   // lane ^ 16 within 32-group
  return __builtin_bit_cast(float,
    __builtin_amdgcn_ds_swizzle(__builtin_bit_cast(int, v), 0x401F));
}

// ---------------- CSR build ----------------
__global__ void k_count(const int* __restrict__ dst, int* __restrict__ counts){
  const int e = blockIdx.x*256 + threadIdx.x;
  if (e < EE) atomicAdd(&counts[dst[e]], 1);
}

__global__ __launch_bounds__(1024) void k_scan(const int* __restrict__ counts,
                                               int* __restrict__ starts,
                                               int* __restrict__ cursor){
  __shared__ int tot[1024];
  const int t = threadIdx.x;
  int loc[16]; int s = 0;
  #pragma unroll
  for (int j=0;j<16;j++){ loc[j] = counts[t*16+j]; s += loc[j]; }
  tot[t] = s;
  __syncthreads();
  for (int o=1;o<1024;o<<=1){
    int v = (t>=o) ? tot[t-o] : 0;
    __syncthreads();
    tot[t] += v;
    __syncthreads();
  }
  int run = tot[t] - s;  // exclusive prefix
  #pragma unroll
  for (int j=0;j<16;j++){ starts[t*16+j] = run; cursor[t*16+j] = run; run += loc[j]; }
  if (t == 1023) starts[NN] = run;
}

// scatter edges into CSR order; pack src | (rel<<28) into one array
__global__ void k_place(const int* __restrict__ src, const int* __restrict__ dst,
                        const int* __restrict__ et, int* __restrict__ cursor,
                        int* __restrict__ sp){
  const int e = blockIdx.x*256 + threadIdx.x;
  if (e < EE){
    const int p = atomicAdd(&cursor[dst[e]], 1);
    sp[p] = (int)(((u32)et[e] << 28) | (u32)src[e]);
  }
}

// ---------------- weight conversion to bf16 ----------------
__global__ void k_convW1(const float* __restrict__ rW, const float* __restrict__ rb,
                         u16* __restrict__ Wst){
  const int hh = blockIdx.y;
  const int k  = blockIdx.x*256 + threadIdx.x;
  if (k >= KS) return;
  float v;
  if (k < KSU){ const int r = k / DIN; const int d = k - r*DIN;
                v = rW[((long)r*DH + hh)*DIN + d]; }
  else if (k < KSU + RR){ const int r = k - KSU; v = rb[(long)r*DH + hh]; }
  else v = 0.f;
  Wst[(long)hh*KS + k] = f2bf(v);
}

__global__ void k_convW2(const float* __restrict__ lW, const float* __restrict__ sW,
                         u16* __restrict__ WB){
  const int idx = blockIdx.x*256 + threadIdx.x;  // exactly 1179648 threads
  const float v = (idx < DH*DH) ? lW[idx] : sW[idx - DH*DH];
  WB[idx] = f2bf(v);
}

// ---------------- phase1 fused: one wave per dst node, VGPR accumulators ----
// s[i, r*384+d] = sum_{p in seg(i)} (dot(x[i],x[srcp])/nc[r]) * x[srcp, d]
// s[i, 3456+r]  = sum norm ; rest of row = 0
// 4 waves/block; 4-edge software pipeline; DPP-based butterfly.
__global__ __launch_bounds__(256, 3) void k_phase1f(const float* __restrict__ x,
                                                    const int* __restrict__ sp,
                                                    const float* __restrict__ nc,
                                                    const int* __restrict__ starts,
                                                    u16* __restrict__ s){
  const int wv = threadIdx.x >> 6;
  const int l  = threadIdx.x & 63;
  const int i  = blockIdx.x*4 + wv;
  const float* xdp = x + (long)i*DIN;
  const f32x2 xd0 = *(const f32x2*)(xdp + 2*l);
  const f32x2 xd1 = *(const f32x2*)(xdp + 128 + 2*l);
  const f32x2 xd2 = *(const f32x2*)(xdp + 256 + 2*l);
  float acc[RR][6];
  float cacc[RR];
  #pragma unroll
  for (int r=0;r<RR;r++){
    cacc[r] = 0.f;
    #pragma unroll
    for (int j=0;j<6;j++) acc[r][j] = 0.f;
  }
  const int e0 = starts[i], e1 = starts[i+1];
  f32x2 Aa={0.f,0.f},Ab={0.f,0.f},Ac={0.f,0.f};
  f32x2 Ba={0.f,0.f},Bb={0.f,0.f},Bc={0.f,0.f};
  f32x2 Ca={0.f,0.f},Cb={0.f,0.f},Cc={0.f,0.f};
  f32x2 Da={0.f,0.f},Db={0.f,0.f},Dc={0.f,0.f};
  u32 qA=0,qB=0,qC=0,qD=0;
  #define LDE(S, QQ, IDX) { const int pe_=(IDX); if (pe_ < e1){ QQ = (u32)sp[pe_]; \
      const float* xs_ = x + (long)(QQ & 0x3FFFu)*DIN; \
      S##a = *(const f32x2*)(xs_ + 2*l); \
      S##b = *(const f32x2*)(xs_ + 128 + 2*l); \
      S##c = *(const f32x2*)(xs_ + 256 + 2*l); } }
  LDE(A,qA,e0) LDE(B,qB,e0+1) LDE(C,qC,e0+2) LDE(D,qD,e0+3)
  #define DOT(u0,u1,u2) (xd0.x*u0.x + xd0.y*u0.y + xd1.x*u1.x + xd1.y*u1.y \
                       + xd2.x*u2.x + xd2.y*u2.y)
  #define UPD(R,P,c0,c1,c2) { cacc[R] += P; \
      acc[R][0] += P*c0.x; acc[R][1] += P*c0.y; acc[R][2] += P*c1.x; \
      acc[R][3] += P*c1.y; acc[R][4] += P*c2.x; acc[R][5] += P*c2.y; }
  #define SW(RQ,P,c0,c1,c2) switch (RQ){ \
      case 0: UPD(0,P,c0,c1,c2); break; case 1: UPD(1,P,c0,c1,c2); break; \
      case 2: UPD(2,P,c0,c1,c2); break; case 3: UPD(3,P,c0,c1,c2); break; \
      case 4: UPD(4,P,c0,c1,c2); break; case 5: UPD(5,P,c0,c1,c2); break; \
      case 6: UPD(6,P,c0,c1,c2); break; case 7: UPD(7,P,c0,c1,c2); break; \
      default: UPD(8,P,c0,c1,c2); break; }
  for (int p=e0; p<e1; p+=4){
    const f32x2 a0=Aa,a1=Ab,a2=Ac, b0=Ba,b1=Bb,b2=Bc;
    const f32x2 c0=Ca,c1=Cb,c2=Cc, d0=Da,d1=Db,d2=Dc;
    const u32 qa=qA, qb=qB, qc=qC, qd=qD;
    const bool h1 = p+1<e1, h2 = p+2<e1, h3 = p+3<e1;
    LDE(A,qA,p+4) LDE(B,qB,p+5) LDE(C,qC,p+6) LDE(D,qD,p+7)
    float pa = DOT(a0,a1,a2), pb = DOT(b0,b1,b2);
    float pc = DOT(c0,c1,c2), pd = DOT(d0,d1,d2);
    // 16-lane rotate-reduce via DPP (VALU), then xor16 (swizzle), xor32 (shfl)
    pa += dppror<1>(pa); pb += dppror<1>(pb); pc += dppror<1>(pc); pd += dppror<1>(pd);
    pa += dppror<2>(pa); pb += dppror<2>(pb); pc += dppror<2>(pc); pd += dppror<2>(pd);
    pa += dppror<4>(pa); pb += dppror<4>(pb); pc += dppror<4>(pc); pd += dppror<4>(pd);
    pa += dppror<8>(pa); pb += dppror<8>(pb); pc += dppror<8>(pc); pd += dppror<8>(pd);
    pa += swz16(pa); pb += swz16(pb); pc += swz16(pc); pd += swz16(pd);
    pa += __shfl_xor(pa,32); pb += __shfl_xor(pb,32);
    pc += __shfl_xor(pc,32); pd += __shfl_xor(pd,32);
    SW(qa>>28, pa, a0,a1,a2);
    if (h1){ SW(qb>>28, pb, b0,b1,b2); }
    if (h2){ SW(qc>>28, pc, c0,c1,c2); }
    if (h3){ SW(qd>>28, pd, d0,d1,d2); }
  }
  #undef LDE
  #undef DOT
  #undef UPD
  #undef SW
  u16* srow = s + (long)i*KS;
  #pragma unroll
  for (int r=0;r<RR;r++){
    const float inv = 1.0f / nc[r];
    #pragma unroll
    for (int seg=0;seg<3;seg++){
      const u32 pk = (u32)f2bf(acc[r][seg*2]*inv)
                   | ((u32)f2bf(acc[r][seg*2+1]*inv) << 16);
      ((u32*)(srow + r*DIN + seg*128))[l] = pk;   // cols seg*128 + {2l, 2l+1}
    }
  }
  float cv = 0.f;
  #pragma unroll
  for (int r=0;r<RR;r++) cv = (l == r) ? cacc[r] : cv;
  if (l < 32){
    const float invl = (l < RR) ? 1.0f/nc[l] : 0.f;
    srow[KSU + l] = f2bf(l < RR ? cv*invl : 0.f);
  }
}

// ---------------- m97-style bf16 GEMM: C = A * B^T (both K-major) ----------------
// grid: x = N-tile (fast), y = M-tile -> consecutive blocks share the A-panel
// (concurrent co-read: A fetched ~once from HBM, reused via L3 across XCDs)
// MODE 0: O0 = relu(C) bf16, stride DH           (gemm1: x1)
// MODE 1: n<768 -> O0 = C+b0[n]; else O1 = C+b1  (gemm2: hm / selfx)
template<int MODE>
__global__ __launch_bounds__(256, 3)
void k_gemm_bt(const u16* __restrict__ A, const u16* __restrict__ B,
               int M, int N, int K,
               u16* __restrict__ O0, u16* __restrict__ O1,
               const float* __restrict__ b0, const float* __restrict__ b1)
{
  __shared__ __align__(16) u16 As[128*32];
  __shared__ __align__(16) u16 Bs[128*32];
  const int t  = threadIdx.x;
  const int wv = t >> 6;
  const int ln = t & 63;
  const int wm = wv >> 1, wn = wv & 1;
  const long m0 = (long)blockIdx.y * 128;
  const long n0 = (long)blockIdx.x * 128;

  const int srow  = ln >> 2;         // staging: lane -> row within 16-row segment
  const int skcol = (ln & 3) * 8;    // k element offset (8 bf16 = 16B)

  f32x4 acc[4][4];
  #pragma unroll
  for (int i=0;i<4;i++)
    #pragma unroll
    for (int j=0;j<4;j++) acc[i][j] = {0.f,0.f,0.f,0.f};

  const int fr = ln & 15, fq = ln >> 4;
  const int nk = K >> 5;
  for (int kb=0; kb<nk; ++kb){
    const long k0 = (long)kb * 32;
    #pragma unroll
    for (int q=0;q<2;q++){
      const int seg = wv*2 + q;
      const int row = seg*16 + srow;
      gll16(A + (m0 + row)*(long)K + k0 + skcol, &As[seg*512]);
      gll16(B + (n0 + row)*(long)K + k0 + skcol, &Bs[seg*512]);
    }
    __syncthreads();
    b16x8 av[4], bv[4];
    #pragma unroll
    for (int i=0;i<4;i++){
      av[i] = *(const b16x8*)&As[(wm*64 + i*16 + fr)*32 + fq*8];
      bv[i] = *(const b16x8*)&Bs[(wn*64 + i*16 + fr)*32 + fq*8];
    }
    #pragma unroll
    for (int i=0;i<4;i++)
      #pragma unroll
      for (int j=0;j<4;j++)
        acc[i][j] = __builtin_amdgcn_mfma_f32_16x16x32_bf16(av[i], bv[j], acc[i][j], 0, 0, 0);
    __syncthreads();
  }

  #pragma unroll
  for (int i=0;i<4;i++){
    #pragma unroll
    for (int j=0;j<4;j++){
      #pragma unroll
      for (int r=0;r<4;r++){
        const long m = m0 + wm*64 + i*16 + fq*4 + r;   // C row = quad*4+reg
        const long n = n0 + wn*64 + j*16 + fr;         // C col = lane&15
        float v = acc[i][j][r];
        if (MODE == 0){
          v = v > 0.f ? v : 0.f;
          O0[m*DH + n] = f2bf(v);
        } else {
          if (n < DH) O0[m*DH + n]      = f2bf(v + b0[n]);
          else        O1[m*DH + (n-DH)] = f2bf(v + b1[n-DH]);
        }
      }
    }
  }
}

// ---------------- phase2 fused with mean-pool: aggr2 + self + relu -> pooled ----
// NPB nodes per 128-thread block; flat edge stream with 8-slot software
// pipeline (prefetch distance 8); sfx rows preloaded; x2 never materialized.
// lane t owns cols {2t,2t+1} of each 256-col third (dword-coalesced bf16 loads).
__global__ __launch_bounds__(128) void k_phase2(const u16* __restrict__ hm,
                                                const u16* __restrict__ sfx,
                                                const int* __restrict__ sp,
                                                const int* __restrict__ starts,
                                                float* __restrict__ pooledP){
  const int t  = threadIdx.x;
  const int i0 = blockIdx.x * NPB;
  const int p0 = starts[i0];
  const int pend = starts[i0 + NPB];
  u32 sf00,sf01,sf02, sf10,sf11,sf12, sf20,sf21,sf22, sf30,sf31,sf32;
  { const u32* sr = (const u32*)(sfx + (long)(i0+0)*DH); sf00=sr[t]; sf01=sr[t+128]; sf02=sr[t+256]; }
  { const u32* sr = (const u32*)(sfx + (long)(i0+1)*DH); sf10=sr[t]; sf11=sr[t+128]; sf12=sr[t+256]; }
  { const u32* sr = (const u32*)(sfx + (long)(i0+2)*DH); sf20=sr[t]; sf21=sr[t+128]; sf22=sr[t+256]; }
  { const u32* sr = (const u32*)(sfx + (long)(i0+3)*DH); sf30=sr[t]; sf31=sr[t+128]; sf32=sr[t+256]; }
  u32 A0=0,A1=0,A2=0,B0=0,B1=0,B2=0,C0=0,C1=0,C2=0,D0=0,D1=0,D2=0;
  u32 E0=0,E1=0,E2=0,F0=0,F1=0,F2=0,G0=0,G1=0,G2=0,H0=0,H1=0,H2=0;
  #define PLD(S, IDX) { const int nf_=(IDX); if (nf_ < pend){ \
      const u32* hr_ = (const u32*)(hm + (long)(((u32)sp[nf_]) & 0x3FFFu)*DH); \
      S##0=hr_[t]; S##1=hr_[t+128]; S##2=hr_[t+256]; } }
  PLD(A,p0)   PLD(B,p0+1) PLD(C,p0+2) PLD(D,p0+3)
  PLD(E,p0+4) PLD(F,p0+5) PLD(G,p0+6) PLD(H,p0+7)
  float a0=0.f,a1=0.f,a2=0.f,a3=0.f,a4=0.f,a5=0.f;
  float q0=0.f,q1=0.f,q2=0.f,q3=0.f,q4=0.f,q5=0.f;
  int i = i0;
  int e1 = starts[i0+1];
  #define FLUSH(K) { float v_; \
    v_=a0+bf2f((u16)sf##K##0);        q0+=fmaxf(v_,0.f); \
    v_=a1+bf2f((u16)(sf##K##0>>16));  q1+=fmaxf(v_,0.f); \
    v_=a2+bf2f((u16)sf##K##1);        q2+=fmaxf(v_,0.f); \
    v_=a3+bf2f((u16)(sf##K##1>>16));  q3+=fmaxf(v_,0.f); \
    v_=a4+bf2f((u16)sf##K##2);        q4+=fmaxf(v_,0.f); \
    v_=a5+bf2f((u16)(sf##K##2>>16));  q5+=fmaxf(v_,0.f); \
    a0=a1=a2=a3=a4=a5=0.f; }
  #define FLUSHI { switch (i - i0){ case 0: FLUSH(0); break; case 1: FLUSH(1); break; \
                   case 2: FLUSH(2); break; default: FLUSH(3); break; } }
  while (i < i0+NPB && e1 == p0){ FLUSHI; ++i; e1 = (i < i0+NPB) ? starts[i+1] : 0x7fffffff; }
  #define STEP(S, K) { const int pe_ = base + K; if (pe_ < pend){ \
      const u32 d0_=S##0, d1_=S##1, d2_=S##2; \
      PLD(S, pe_ + 8); \
      a0+=bf2f((u16)d0_); a1+=bf2f((u16)(d0_>>16)); \
      a2+=bf2f((u16)d1_); a3+=bf2f((u16)(d1_>>16)); \
      a4+=bf2f((u16)d2_); a5+=bf2f((u16)(d2_>>16)); \
      while (i < i0+NPB && pe_+1 == e1){ FLUSHI; ++i; \
        e1 = (i < i0+NPB) ? starts[i+1] : 0x7fffffff; } } }
  for (int base = p0; base < pend; base += 8){
    STEP(A,0) STEP(B,1) STEP(C,2) STEP(D,3)
    STEP(E,4) STEP(F,5) STEP(G,6) STEP(H,7)
  }
  while (i < i0+NPB){ FLUSHI; ++i; }
  #undef PLD
  #undef FLUSH
  #undef FLUSHI
  #undef STEP
  float* pd = pooledP + (blockIdx.x & (PCOP-1)) * DH;
  atomicAdd(&pd[2*t],       q0);
  atomicAdd(&pd[2*t+1],     q1);
  atomicAdd(&pd[256+2*t],   q2);
  atomicAdd(&pd[256+2*t+1], q3);
  atomicAdd(&pd[512+2*t],   q4);
  atomicAdd(&pd[512+2*t+1], q5);
}

__global__ __launch_bounds__(256) void k_final(const float* __restrict__ pooledP,
                                               const float* __restrict__ oW,
                                               const float* __restrict__ ob,
                                               float* __restrict__ out){
  __shared__ float ps[DH];
  __shared__ float red[256];
  const int t = threadIdx.x;
  for (int h=t; h<DH; h+=256){
    float s = 0.f;
    #pragma unroll
    for (int c=0;c<PCOP;c++) s += pooledP[c*DH + h];
    ps[h] = s;
  }
  __syncthreads();
  for (int c=0;c<5;c++){
    float p = 0.f;
    for (int h=t; h<DH; h+=256) p += ps[h]*oW[c*DH + h];
    red[t] = p; __syncthreads();
    for (int o=128;o;o>>=1){ if (t<o) red[t]+=red[t+o]; __syncthreads(); }
    if (t == 0) out[c] = red[0]*(1.f/(float)NN) + ob[c];
    __syncthreads();
  }
}

// ---------------- launch ----------------
extern "C" void kernel_launch(void* const* d_in, const int* in_sizes, int n_in,
                              void* d_out, int out_size, void* d_ws, size_t ws_size,
                              hipStream_t stream)
{
  (void)in_sizes; (void)n_in; (void)out_size; (void)ws_size;
  const float* x     = (const float*)d_in[0];
  const int*   ei    = (const int*)  d_in[1];   // [2][E]: row0=src, row1=dst
  const int*   et    = (const int*)  d_in[2];
  const float* relW  = (const float*)d_in[3];
  const float* relb  = (const float*)d_in[4];
  const float* nc    = (const float*)d_in[5];
  const float* linW  = (const float*)d_in[6];
  const float* linb  = (const float*)d_in[7];
  const float* selfW = (const float*)d_in[8];
  const float* selfb = (const float*)d_in[9];
  const float* outW  = (const float*)d_in[10];
  const float* outb  = (const float*)d_in[11];
  float* out = (float*)d_out;

  // workspace layout (256B aligned); hm/selfx alias S (dead after gemm1)
  u8* w = (u8*)d_ws;
  int*   counts = (int*)(w + 0);              // 64 KB
  int*   starts = (int*)(w + 65536);          // 16385*4
  int*   cursor = (int*)(w + 131328);         // 64 KB
  int*   srcp   = (int*)(w + 196864);         // 1 MB (packed src|rel<<28)
  u16*   Wst    = (u16*)(w + 4391168);        // 768*3488*2  = 5.36 MB
  u16*   WB     = (u16*)(w + 9748736);        // 1536*768*2  = 2.36 MB
  u16*   x1     = (u16*)(w + 12108032);       // 16384*768*2 = 25.2 MB
  u16*   S      = (u16*)(w + 37276928);       // 16384*3488*2 = 114.3 MB
  u16*   hm     = S;                          // alias: 25.2 MB
  u16*   sfx    = (u16*)(w + 37276928 + 25165824);
  // partial pooled copies live in S's tail (dead after gemm1 reads S)
  float* pooledP = (float*)(w + 37276928 + 50331648);  // PCOP*768*4 = 48 KB

  const int* esrc = ei;
  const int* edst = ei + EE;

  hipMemsetAsync(counts, 0, NN*sizeof(int), stream);

  k_count <<<EE/256, 256, 0, stream>>>(edst, counts);
  k_scan  <<<1, 1024, 0, stream>>>(counts, starts, cursor);
  k_place <<<EE/256, 256, 0, stream>>>(esrc, edst, et, cursor, srcp);
  k_convW1<<<dim3(14, DH), 256, 0, stream>>>(relW, relb, Wst);
  k_convW2<<<(2*DH*DH)/256, 256, 0, stream>>>(linW, selfW, WB);
  k_phase1f<<<NN/4, 256, 0, stream>>>(x, srcp, nc, starts, S);
  k_gemm_bt<0><<<dim3(DH/128, NN/128), 256, 0, stream>>>(
      S, Wst, NN, DH, KS, x1, (u16*)nullptr, (const float*)nullptr, (const float*)nullptr);
  // S fully consumed by gemm1; its tail is now free for the pooled partials
  hipMemsetAsync(pooledP, 0, PCOP*DH*sizeof(float), stream);
  k_gemm_bt<1><<<dim3(2*DH/128, NN/128), 256, 0, stream>>>(
      x1, WB, NN, 2*DH, DH, hm, sfx, linb, selfb);
  k_phase2<<<NN/NPB, 128, 0, stream>>>(hm, sfx, srcp, starts, pooledP);
  k_final <<<1, 256, 0, stream>>>(pooledP, outW, outb, out);
}

// Round 3
// 449.771 us; speedup vs baseline: 1.1838x; 1.0601x over previous
//
#include <hip/hip_runtime.h>

typedef unsigned char  u8;
typedef unsigned short u16;
typedef unsigned int   u32;

#define NN   16384     // nodes
#define EE   262144    // edges
#define RR   9         // relations
#define DIN  384
#define DH   768
#define KSU  3456      // RR*DIN
#define KS   3488      // KSU + 9 cnt cols + pad to 32
#define NPB  4         // nodes per block in phase2
#define PCOP 16        // partial pooled copies

typedef float  f32x4 __attribute__((ext_vector_type(4)));
typedef float  f32x2 __attribute__((ext_vector_type(2)));
typedef u32    u32x2 __attribute__((ext_vector_type(2)));
typedef __bf16 b16x8 __attribute__((ext_vector_type(8)));

__device__ __forceinline__ u16 f2bf(float f){
  u32 u = __builtin_bit_cast(u32, f);
  u += 0x7fffu + ((u >> 16) & 1u);          // RNE
  return (u16)(u >> 16);
}
__device__ __forceinline__ float bf2f(u16 h){
  u32 u = ((u32)h) << 16;
  return __builtin_bit_cast(float, u);
}
__device__ __forceinline__ u32 pkbf(float a, float b){
  return (u32)f2bf(a) | ((u32)f2bf(b) << 16);
}
// async global->LDS, 16B per lane; LDS dest = wave-uniform base + lane*16
__device__ __forceinline__ void gll16(const void* g, void* l){
  __builtin_amdgcn_global_load_lds((const __attribute__((address_space(1))) void*)g,
                                   (__attribute__((address_space(3))) void*)l, 16, 0, 0);
}
// DPP row rotate (16-lane rows), full-rate VALU — no LDS pipe
template<int N> __device__ __forceinline__ float dppror(float v){
  return __builtin_bit_cast(float,
    __builtin_amdgcn_update_dpp(0, __builtin_bit_cast(int, v), 0x120+N, 0xF, 0xF, true));
}
__device__ __forceinline__ float swz16(float v){   // lane ^ 16 within 32-group
  return __builtin_bit_cast(float,
    __builtin_amdgcn_ds_swizzle(__builtin_bit_cast(int, v), 0x401F));
}

// ---------------- CSR build ----------------
__global__ void k_count(const int* __restrict__ dst, int* __restrict__ counts){
  const int e = blockIdx.x*256 + threadIdx.x;
  if (e < EE) atomicAdd(&counts[dst[e]], 1);
}

__global__ __launch_bounds__(1024) void k_scan(const int* __restrict__ counts,
                                               int* __restrict__ starts,
                                               int* __restrict__ cursor){
  __shared__ int tot[1024];
  const int t = threadIdx.x;
  int loc[16]; int s = 0;
  #pragma unroll
  for (int j=0;j<16;j++){ loc[j] = counts[t*16+j]; s += loc[j]; }
  tot[t] = s;
  __syncthreads();
  for (int o=1;o<1024;o<<=1){
    int v = (t>=o) ? tot[t-o] : 0;
    __syncthreads();
    tot[t] += v;
    __syncthreads();
  }
  int run = tot[t] - s;  // exclusive prefix
  #pragma unroll
  for (int j=0;j<16;j++){ starts[t*16+j] = run; cursor[t*16+j] = run; run += loc[j]; }
  if (t == 1023) starts[NN] = run;
}

// scatter edges into CSR order; pack src | (rel<<28) into one array
__global__ void k_place(const int* __restrict__ src, const int* __restrict__ dst,
                        const int* __restrict__ et, int* __restrict__ cursor,
                        int* __restrict__ sp){
  const int e = blockIdx.x*256 + threadIdx.x;
  if (e < EE){
    const int p = atomicAdd(&cursor[dst[e]], 1);
    sp[p] = (int)(((u32)et[e] << 28) | (u32)src[e]);
  }
}

// ---------------- weight conversion to bf16 ----------------
__global__ void k_convW1(const float* __restrict__ rW, const float* __restrict__ rb,
                         u16* __restrict__ Wst){
  const int hh = blockIdx.y;
  const int k  = blockIdx.x*256 + threadIdx.x;
  if (k >= KS) return;
  float v;
  if (k < KSU){ const int r = k / DIN; const int d = k - r*DIN;
                v = rW[((long)r*DH + hh)*DIN + d]; }
  else if (k < KSU + RR){ const int r = k - KSU; v = rb[(long)r*DH + hh]; }
  else v = 0.f;
  Wst[(long)hh*KS + k] = f2bf(v);
}

__global__ void k_convW2(const float* __restrict__ lW, const float* __restrict__ sW,
                         u16* __restrict__ WB){
  const int idx = blockIdx.x*256 + threadIdx.x;  // exactly 1179648 threads
  const float v = (idx < DH*DH) ? lW[idx] : sW[idx - DH*DH];
  WB[idx] = f2bf(v);
}

// ---------------- phase1 fused: one wave per dst node, VGPR accumulators ----
// s[i, r*384+d] = sum_{p in seg(i)} (dot(x[i],x[srcp])/nc[r]) * x[srcp, d]
// s[i, 3456+r]  = sum norm ; rest of row = 0
// 4 waves/block; 4-edge software pipeline; DPP-based butterfly.
// lane l owns cols {4l..4l+3} (dwordx4) and {256+2l,256+2l+1} (dwordx2):
// 2 VMEM ops per gathered row instead of 3.
__global__ __launch_bounds__(256, 3) void k_phase1f(const float* __restrict__ x,
                                                    const int* __restrict__ sp,
                                                    const float* __restrict__ nc,
                                                    const int* __restrict__ starts,
                                                    u16* __restrict__ s){
  const int wv = threadIdx.x >> 6;
  const int l  = threadIdx.x & 63;
  const int i  = blockIdx.x*4 + wv;
  const float* xdp = x + (long)i*DIN;
  const f32x4 xq = *(const f32x4*)(xdp + 4*l);
  const f32x2 xr = *(const f32x2*)(xdp + 256 + 2*l);
  float acc[RR][6];
  float cacc[RR];
  #pragma unroll
  for (int r=0;r<RR;r++){
    cacc[r] = 0.f;
    #pragma unroll
    for (int j=0;j<6;j++) acc[r][j] = 0.f;
  }
  const int e0 = starts[i], e1 = starts[i+1];
  f32x4 Aq={0,0,0,0}, Bq={0,0,0,0}, Cq={0,0,0,0}, Dq={0,0,0,0};
  f32x2 Ar={0,0}, Br={0,0}, Cr={0,0}, Dr={0,0};
  u32 qA=0,qB=0,qC=0,qD=0;
  #define LDE(S, QQ, IDX) { const int pe_=(IDX); if (pe_ < e1){ QQ = (u32)sp[pe_]; \
      const float* xs_ = x + (long)(QQ & 0x3FFFu)*DIN; \
      S##q = *(const f32x4*)(xs_ + 4*l); \
      S##r = *(const f32x2*)(xs_ + 256 + 2*l); } }
  LDE(A,qA,e0) LDE(B,qB,e0+1) LDE(C,qC,e0+2) LDE(D,qD,e0+3)
  #define DOT(uq,ur) (xq.x*uq.x + xq.y*uq.y + xq.z*uq.z + xq.w*uq.w \
                    + xr.x*ur.x + xr.y*ur.y)
  #define UPD(R,P,cq,cr) { cacc[R] += P; \
      acc[R][0] += P*cq.x; acc[R][1] += P*cq.y; acc[R][2] += P*cq.z; \
      acc[R][3] += P*cq.w; acc[R][4] += P*cr.x; acc[R][5] += P*cr.y; }
  #define SW(RQ,P,cq,cr) switch (RQ){ \
      case 0: UPD(0,P,cq,cr); break; case 1: UPD(1,P,cq,cr); break; \
      case 2: UPD(2,P,cq,cr); break; case 3: UPD(3,P,cq,cr); break; \
      case 4: UPD(4,P,cq,cr); break; case 5: UPD(5,P,cq,cr); break; \
      case 6: UPD(6,P,cq,cr); break; case 7: UPD(7,P,cq,cr); break; \
      default: UPD(8,P,cq,cr); break; }
  for (int p=e0; p<e1; p+=4){
    const f32x4 aq=Aq, bq=Bq, cq=Cq, dq=Dq;
    const f32x2 ar=Ar, br=Br, cr=Cr, dr=Dr;
    const u32 qa=qA, qb=qB, qc=qC, qd=qD;
    const bool h1 = p+1<e1, h2 = p+2<e1, h3 = p+3<e1;
    LDE(A,qA,p+4) LDE(B,qB,p+5) LDE(C,qC,p+6) LDE(D,qD,p+7)
    float pa = DOT(aq,ar), pb = DOT(bq,br);
    float pc = DOT(cq,cr), pd = DOT(dq,dr);
    // 16-lane rotate-reduce via DPP (VALU), then xor16 (swizzle), xor32 (shfl)
    pa += dppror<1>(pa); pb += dppror<1>(pb); pc += dppror<1>(pc); pd += dppror<1>(pd);
    pa += dppror<2>(pa); pb += dppror<2>(pb); pc += dppror<2>(pc); pd += dppror<2>(pd);
    pa += dppror<4>(pa); pb += dppror<4>(pb); pc += dppror<4>(pc); pd += dppror<4>(pd);
    pa += dppror<8>(pa); pb += dppror<8>(pb); pc += dppror<8>(pc); pd += dppror<8>(pd);
    pa += swz16(pa); pb += swz16(pb); pc += swz16(pc); pd += swz16(pd);
    pa += __shfl_xor(pa,32); pb += __shfl_xor(pb,32);
    pc += __shfl_xor(pc,32); pd += __shfl_xor(pd,32);
    SW(qa>>28, pa, aq,ar);
    if (h1){ SW(qb>>28, pb, bq,br); }
    if (h2){ SW(qc>>28, pc, cq,cr); }
    if (h3){ SW(qd>>28, pd, dq,dr); }
  }
  #undef LDE
  #undef DOT
  #undef UPD
  #undef SW
  u16* srow = s + (long)i*KS;
  #pragma unroll
  for (int r=0;r<RR;r++){
    const float inv = 1.0f / nc[r];
    const u32 pk0 = pkbf(acc[r][0]*inv, acc[r][1]*inv);
    const u32 pk1 = pkbf(acc[r][2]*inv, acc[r][3]*inv);
    const u32 pk2 = pkbf(acc[r][4]*inv, acc[r][5]*inv);
    *(u32x2*)(srow + r*DIN + 4*l) = (u32x2){pk0, pk1};   // cols 4l..4l+3
    ((u32*)(srow + r*DIN + 256))[l] = pk2;               // cols 256+{2l,2l+1}
  }
  float cv = 0.f;
  #pragma unroll
  for (int r=0;r<RR;r++) cv = (l == r) ? cacc[r] : cv;
  if (l < 32){
    const float invl = (l < RR) ? 1.0f/nc[l] : 0.f;
    srow[KSU + l] = f2bf(l < RR ? cv*invl : 0.f);
  }
}

// ---------------- m97-style bf16 GEMM: C = A * B^T (both K-major) ----------------
// 1-D grid, bijective XCD-chunk swizzle: lg = (bid%8)*cpx + bid/8 so all NT
// n-tiles sharing an A-panel land on the SAME XCD's L2 (panel fetched once).
// NT = n-tiles (6 or 12); cpx divisible by NT so sharers never straddle chunks.
// MODE 0: O0 = relu(C) bf16, stride DH           (gemm1: x1)
// MODE 1: n<768 -> O0 = C+b0[n]; else O1 = C+b1  (gemm2: hm / selfx)
template<int MODE, int NT>
__global__ __launch_bounds__(256, 3)
void k_gemm_bt(const u16* __restrict__ A, const u16* __restrict__ B,
               int K,
               u16* __restrict__ O0, u16* __restrict__ O1,
               const float* __restrict__ b0, const float* __restrict__ b1)
{
  __shared__ __align__(16) u16 As[128*32];
  __shared__ __align__(16) u16 Bs[128*32];
  const int cpx = gridDim.x >> 3;
  const int bid = blockIdx.x;
  const int lg  = (bid & 7)*cpx + (bid >> 3);
  const int mt  = lg / NT;
  const long m0 = (long)mt * 128;
  const long n0 = (long)(lg - mt*NT) * 128;
  const int t  = threadIdx.x;
  const int wv = t >> 6;
  const int ln = t & 63;
  const int wm = wv >> 1, wn = wv & 1;

  const int srow  = ln >> 2;         // staging: lane -> row within 16-row segment
  const int skcol = (ln & 3) * 8;    // k element offset (8 bf16 = 16B)

  f32x4 acc[4][4];
  #pragma unroll
  for (int i=0;i<4;i++)
    #pragma unroll
    for (int j=0;j<4;j++) acc[i][j] = {0.f,0.f,0.f,0.f};

  const int fr = ln & 15, fq = ln >> 4;
  const int nk = K >> 5;
  for (int kb=0; kb<nk; ++kb){
    const long k0 = (long)kb * 32;
    #pragma unroll
    for (int q=0;q<2;q++){
      const int seg = wv*2 + q;
      const int row = seg*16 + srow;
      gll16(A + (m0 + row)*(long)K + k0 + skcol, &As[seg*512]);
      gll16(B + (n0 + row)*(long)K + k0 + skcol, &Bs[seg*512]);
    }
    __syncthreads();
    b16x8 av[4], bv[4];
    #pragma unroll
    for (int i=0;i<4;i++){
      av[i] = *(const b16x8*)&As[(wm*64 + i*16 + fr)*32 + fq*8];
      bv[i] = *(const b16x8*)&Bs[(wn*64 + i*16 + fr)*32 + fq*8];
    }
    #pragma unroll
    for (int i=0;i<4;i++)
      #pragma unroll
      for (int j=0;j<4;j++)
        acc[i][j] = __builtin_amdgcn_mfma_f32_16x16x32_bf16(av[i], bv[j], acc[i][j], 0, 0, 0);
    __syncthreads();
  }

  #pragma unroll
  for (int i=0;i<4;i++){
    #pragma unroll
    for (int j=0;j<4;j++){
      #pragma unroll
      for (int r=0;r<4;r++){
        const long m = m0 + wm*64 + i*16 + fq*4 + r;   // C row = quad*4+reg
        const long n = n0 + wn*64 + j*16 + fr;         // C col = lane&15
        float v = acc[i][j][r];
        if (MODE == 0){
          v = v > 0.f ? v : 0.f;
          O0[m*DH + n] = f2bf(v);
        } else {
          if (n < DH) O0[m*DH + n]      = f2bf(v + b0[n]);
          else        O1[m*DH + (n-DH)] = f2bf(v + b1[n-DH]);
        }
      }
    }
  }
}

// ---------------- phase2 fused with mean-pool: aggr2 + self + relu -> pooled ----
// NPB nodes per 128-thread block; flat edge stream with 8-slot software
// pipeline (prefetch distance 8); sfx rows preloaded; x2 never materialized.
// lane t owns cols {2t,2t+1} of each 256-col third (dword-coalesced bf16 loads).
__global__ __launch_bounds__(128) void k_phase2(const u16* __restrict__ hm,
                                                const u16* __restrict__ sfx,
                                                const int* __restrict__ sp,
                                                const int* __restrict__ starts,
                                                float* __restrict__ pooledP){
  const int t  = threadIdx.x;
  const int i0 = blockIdx.x * NPB;
  const int p0 = starts[i0];
  const int pend = starts[i0 + NPB];
  u32 sf00,sf01,sf02, sf10,sf11,sf12, sf20,sf21,sf22, sf30,sf31,sf32;
  { const u32* sr = (const u32*)(sfx + (long)(i0+0)*DH); sf00=sr[t]; sf01=sr[t+128]; sf02=sr[t+256]; }
  { const u32* sr = (const u32*)(sfx + (long)(i0+1)*DH); sf10=sr[t]; sf11=sr[t+128]; sf12=sr[t+256]; }
  { const u32* sr = (const u32*)(sfx + (long)(i0+2)*DH); sf20=sr[t]; sf21=sr[t+128]; sf22=sr[t+256]; }
  { const u32* sr = (const u32*)(sfx + (long)(i0+3)*DH); sf30=sr[t]; sf31=sr[t+128]; sf32=sr[t+256]; }
  u32 A0=0,A1=0,A2=0,B0=0,B1=0,B2=0,C0=0,C1=0,C2=0,D0=0,D1=0,D2=0;
  u32 E0=0,E1=0,E2=0,F0=0,F1=0,F2=0,G0=0,G1=0,G2=0,H0=0,H1=0,H2=0;
  #define PLD(S, IDX) { const int nf_=(IDX); if (nf_ < pend){ \
      const u32* hr_ = (const u32*)(hm + (long)(((u32)sp[nf_]) & 0x3FFFu)*DH); \
      S##0=hr_[t]; S##1=hr_[t+128]; S##2=hr_[t+256]; } }
  PLD(A,p0)   PLD(B,p0+1) PLD(C,p0+2) PLD(D,p0+3)
  PLD(E,p0+4) PLD(F,p0+5) PLD(G,p0+6) PLD(H,p0+7)
  float a0=0.f,a1=0.f,a2=0.f,a3=0.f,a4=0.f,a5=0.f;
  float q0=0.f,q1=0.f,q2=0.f,q3=0.f,q4=0.f,q5=0.f;
  int i = i0;
  int e1 = starts[i0+1];
  #define FLUSH(K) { float v_; \
    v_=a0+bf2f((u16)sf##K##0);        q0+=fmaxf(v_,0.f); \
    v_=a1+bf2f((u16)(sf##K##0>>16));  q1+=fmaxf(v_,0.f); \
    v_=a2+bf2f((u16)sf##K##1);        q2+=fmaxf(v_,0.f); \
    v_=a3+bf2f((u16)(sf##K##1>>16));  q3+=fmaxf(v_,0.f); \
    v_=a4+bf2f((u16)sf##K##2);        q4+=fmaxf(v_,0.f); \
    v_=a5+bf2f((u16)(sf##K##2>>16));  q5+=fmaxf(v_,0.f); \
    a0=a1=a2=a3=a4=a5=0.f; }
  #define FLUSHI { switch (i - i0){ case 0: FLUSH(0); break; case 1: FLUSH(1); break; \
                   case 2: FLUSH(2); break; default: FLUSH(3); break; } }
  while (i < i0+NPB && e1 == p0){ FLUSHI; ++i; e1 = (i < i0+NPB) ? starts[i+1] : 0x7fffffff; }
  #define STEP(S, K) { const int pe_ = base + K; if (pe_ < pend){ \
      const u32 d0_=S##0, d1_=S##1, d2_=S##2; \
      PLD(S, pe_ + 8); \
      a0+=bf2f((u16)d0_); a1+=bf2f((u16)(d0_>>16)); \
      a2+=bf2f((u16)d1_); a3+=bf2f((u16)(d1_>>16)); \
      a4+=bf2f((u16)d2_); a5+=bf2f((u16)(d2_>>16)); \
      while (i < i0+NPB && pe_+1 == e1){ FLUSHI; ++i; \
        e1 = (i < i0+NPB) ? starts[i+1] : 0x7fffffff; } } }
  for (int base = p0; base < pend; base += 8){
    STEP(A,0) STEP(B,1) STEP(C,2) STEP(D,3)
    STEP(E,4) STEP(F,5) STEP(G,6) STEP(H,7)
  }
  while (i < i0+NPB){ FLUSHI; ++i; }
  #undef PLD
  #undef FLUSH
  #undef FLUSHI
  #undef STEP
  float* pd = pooledP + (blockIdx.x & (PCOP-1)) * DH;
  atomicAdd(&pd[2*t],       q0);
  atomicAdd(&pd[2*t+1],     q1);
  atomicAdd(&pd[256+2*t],   q2);
  atomicAdd(&pd[256+2*t+1], q3);
  atomicAdd(&pd[512+2*t],   q4);
  atomicAdd(&pd[512+2*t+1], q5);
}

__global__ __launch_bounds__(256) void k_final(const float* __restrict__ pooledP,
                                               const float* __restrict__ oW,
                                               const float* __restrict__ ob,
                                               float* __restrict__ out){
  __shared__ float ps[DH];
  __shared__ float red[256];
  const int t = threadIdx.x;
  for (int h=t; h<DH; h+=256){
    float s = 0.f;
    #pragma unroll
    for (int c=0;c<PCOP;c++) s += pooledP[c*DH + h];
    ps[h] = s;
  }
  __syncthreads();
  for (int c=0;c<5;c++){
    float p = 0.f;
    for (int h=t; h<DH; h+=256) p += ps[h]*oW[c*DH + h];
    red[t] = p; __syncthreads();
    for (int o=128;o;o>>=1){ if (t<o) red[t]+=red[t+o]; __syncthreads(); }
    if (t == 0) out[c] = red[0]*(1.f/(float)NN) + ob[c];
    __syncthreads();
  }
}

// ---------------- launch ----------------
extern "C" void kernel_launch(void* const* d_in, const int* in_sizes, int n_in,
                              void* d_out, int out_size, void* d_ws, size_t ws_size,
                              hipStream_t stream)
{
  (void)in_sizes; (void)n_in; (void)out_size; (void)ws_size;
  const float* x     = (const float*)d_in[0];
  const int*   ei    = (const int*)  d_in[1];   // [2][E]: row0=src, row1=dst
  const int*   et    = (const int*)  d_in[2];
  const float* relW  = (const float*)d_in[3];
  const float* relb  = (const float*)d_in[4];
  const float* nc    = (const float*)d_in[5];
  const float* linW  = (const float*)d_in[6];
  const float* linb  = (const float*)d_in[7];
  const float* selfW = (const float*)d_in[8];
  const float* selfb = (const float*)d_in[9];
  const float* outW  = (const float*)d_in[10];
  const float* outb  = (const float*)d_in[11];
  float* out = (float*)d_out;

  // workspace layout (256B aligned); hm/selfx alias S (dead after gemm1)
  u8* w = (u8*)d_ws;
  int*   counts = (int*)(w + 0);              // 64 KB
  int*   starts = (int*)(w + 65536);          // 16385*4
  int*   cursor = (int*)(w + 131328);         // 64 KB
  int*   srcp   = (int*)(w + 196864);         // 1 MB (packed src|rel<<28)
  u16*   Wst    = (u16*)(w + 4391168);        // 768*3488*2  = 5.36 MB
  u16*   WB     = (u16*)(w + 9748736);        // 1536*768*2  = 2.36 MB
  u16*   x1     = (u16*)(w + 12108032);       // 16384*768*2 = 25.2 MB
  u16*   S      = (u16*)(w + 37276928);       // 16384*3488*2 = 114.3 MB
  u16*   hm     = S;                          // alias: 25.2 MB
  u16*   sfx    = (u16*)(w + 37276928 + 25165824);
  // partial pooled copies live in S's tail (dead after gemm1 reads S)
  float* pooledP = (float*)(w + 37276928 + 50331648);  // PCOP*768*4 = 48 KB

  const int* esrc = ei;
  const int* edst = ei + EE;

  hipMemsetAsync(counts, 0, NN*sizeof(int), stream);

  k_count <<<EE/256, 256, 0, stream>>>(edst, counts);
  k_scan  <<<1, 1024, 0, stream>>>(counts, starts, cursor);
  k_place <<<EE/256, 256, 0, stream>>>(esrc, edst, et, cursor, srcp);
  k_convW1<<<dim3(14, DH), 256, 0, stream>>>(relW, relb, Wst);
  k_convW2<<<(2*DH*DH)/256, 256, 0, stream>>>(linW, selfW, WB);
  k_phase1f<<<NN/4, 256, 0, stream>>>(x, srcp, nc, starts, S);
  k_gemm_bt<0,6><<<(NN/128)*(DH/128), 256, 0, stream>>>(
      S, Wst, KS, x1, (u16*)nullptr, (const float*)nullptr, (const float*)nullptr);
  // S fully consumed by gemm1; its tail is now free for the pooled partials
  hipMemsetAsync(pooledP, 0, PCOP*DH*sizeof(float), stream);
  k_gemm_bt<1,12><<<(NN/128)*(2*DH/128), 256, 0, stream>>>(
      x1, WB, DH, hm, sfx, linb, selfb);
  k_phase2<<<NN/NPB, 128, 0, stream>>>(hm, sfx, srcp, starts, pooledP);
  k_final <<<1, 256, 0, stream>>>(pooledP, outW, outb, out);
}

// Round 4
// 448.540 us; speedup vs baseline: 1.1871x; 1.0027x over previous
//
#include <hip/hip_runtime.h>

typedef unsigned char  u8;
typedef unsigned short u16;
typedef unsigned int   u32;

#define NN   16384     // nodes
#define EE   262144    // edges
#define RR   9         // relations
#define DIN  384
#define DH   768
#define KSU  3456      // RR*DIN
#define KS   3488      // KSU + 9 cnt cols + pad to 32
#define NPB  4         // nodes per block in phase2
#define PCOP 16        // partial pooled copies

typedef float  f32x4 __attribute__((ext_vector_type(4)));
typedef float  f32x2 __attribute__((ext_vector_type(2)));
typedef u32    u32x2 __attribute__((ext_vector_type(2)));
typedef __bf16 b16x8 __attribute__((ext_vector_type(8)));

__device__ __forceinline__ u16 f2bf(float f){
  u32 u = __builtin_bit_cast(u32, f);
  u += 0x7fffu + ((u >> 16) & 1u);          // RNE
  return (u16)(u >> 16);
}
__device__ __forceinline__ float bf2f(u16 h){
  u32 u = ((u32)h) << 16;
  return __builtin_bit_cast(float, u);
}
__device__ __forceinline__ u32 pkbf(float a, float b){
  return (u32)f2bf(a) | ((u32)f2bf(b) << 16);
}
// async global->LDS, 16B per lane; LDS dest = wave-uniform base + lane*16
__device__ __forceinline__ void gll16(const void* g, void* l){
  __builtin_amdgcn_global_load_lds((const __attribute__((address_space(1))) void*)g,
                                   (__attribute__((address_space(3))) void*)l, 16, 0, 0);
}
// DPP row rotate (16-lane rows), full-rate VALU — no LDS pipe
template<int N> __device__ __forceinline__ float dppror(float v){
  return __builtin_bit_cast(float,
    __builtin_amdgcn_update_dpp(0, __builtin_bit_cast(int, v), 0x120+N, 0xF, 0xF, true));
}
__device__ __forceinline__ float swz16(float v){   // lane ^ 16 within 32-group
  return __builtin_bit_cast(float,
    __builtin_amdgcn_ds_swizzle(__builtin_bit_cast(int, v), 0x401F));
}

// ---------------- CSR build ----------------
__global__ void k_count(const int* __restrict__ dst, int* __restrict__ counts){
  const int e = blockIdx.x*256 + threadIdx.x;
  if (e < EE) atomicAdd(&counts[dst[e]], 1);
}

__global__ __launch_bounds__(1024) void k_scan(const int* __restrict__ counts,
                                               int* __restrict__ starts,
                                               int* __restrict__ cursor){
  __shared__ int tot[1024];
  const int t = threadIdx.x;
  int loc[16]; int s = 0;
  #pragma unroll
  for (int j=0;j<16;j++){ loc[j] = counts[t*16+j]; s += loc[j]; }
  tot[t] = s;
  __syncthreads();
  for (int o=1;o<1024;o<<=1){
    int v = (t>=o) ? tot[t-o] : 0;
    __syncthreads();
    tot[t] += v;
    __syncthreads();
  }
  int run = tot[t] - s;  // exclusive prefix
  #pragma unroll
  for (int j=0;j<16;j++){ starts[t*16+j] = run; cursor[t*16+j] = run; run += loc[j]; }
  if (t == 1023) starts[NN] = run;
}

// scatter edges into CSR order; pack src | (rel<<28) into one array
__global__ void k_place(const int* __restrict__ src, const int* __restrict__ dst,
                        const int* __restrict__ et, int* __restrict__ cursor,
                        int* __restrict__ sp){
  const int e = blockIdx.x*256 + threadIdx.x;
  if (e < EE){
    const int p = atomicAdd(&cursor[dst[e]], 1);
    sp[p] = (int)(((u32)et[e] << 28) | (u32)src[e]);
  }
}

// ---------------- weight conversion to bf16 ----------------
__global__ void k_convW1(const float* __restrict__ rW, const float* __restrict__ rb,
                         u16* __restrict__ Wst){
  const int hh = blockIdx.y;
  const int k  = blockIdx.x*256 + threadIdx.x;
  if (k >= KS) return;
  float v;
  if (k < KSU){ const int r = k / DIN; const int d = k - r*DIN;
                v = rW[((long)r*DH + hh)*DIN + d]; }
  else if (k < KSU + RR){ const int r = k - KSU; v = rb[(long)r*DH + hh]; }
  else v = 0.f;
  Wst[(long)hh*KS + k] = f2bf(v);
}

__global__ void k_convW2(const float* __restrict__ lW, const float* __restrict__ sW,
                         u16* __restrict__ WB){
  const int idx = blockIdx.x*256 + threadIdx.x;  // exactly 1179648 threads
  const float v = (idx < DH*DH) ? lW[idx] : sW[idx - DH*DH];
  WB[idx] = f2bf(v);
}

// ---------------- phase1 fused: one wave per dst node, VGPR accumulators ----
__global__ __launch_bounds__(256, 3) void k_phase1f(const float* __restrict__ x,
                                                    const int* __restrict__ sp,
                                                    const float* __restrict__ nc,
                                                    const int* __restrict__ starts,
                                                    u16* __restrict__ s){
  const int wv = threadIdx.x >> 6;
  const int l  = threadIdx.x & 63;
  const int i  = blockIdx.x*4 + wv;
  const float* xdp = x + (long)i*DIN;
  const f32x4 xq = *(const f32x4*)(xdp + 4*l);
  const f32x2 xr = *(const f32x2*)(xdp + 256 + 2*l);
  float acc[RR][6];
  float cacc[RR];
  #pragma unroll
  for (int r=0;r<RR;r++){
    cacc[r] = 0.f;
    #pragma unroll
    for (int j=0;j<6;j++) acc[r][j] = 0.f;
  }
  const int e0 = starts[i], e1 = starts[i+1];
  f32x4 Aq={0,0,0,0}, Bq={0,0,0,0}, Cq={0,0,0,0}, Dq={0,0,0,0};
  f32x2 Ar={0,0}, Br={0,0}, Cr={0,0}, Dr={0,0};
  u32 qA=0,qB=0,qC=0,qD=0;
  #define LDE(S, QQ, IDX) { const int pe_=(IDX); if (pe_ < e1){ QQ = (u32)sp[pe_]; \
      const float* xs_ = x + (long)(QQ & 0x3FFFu)*DIN; \
      S##q = *(const f32x4*)(xs_ + 4*l); \
      S##r = *(const f32x2*)(xs_ + 256 + 2*l); } }
  LDE(A,qA,e0) LDE(B,qB,e0+1) LDE(C,qC,e0+2) LDE(D,qD,e0+3)
  #define DOT(uq,ur) (xq.x*uq.x + xq.y*uq.y + xq.z*uq.z + xq.w*uq.w \
                    + xr.x*ur.x + xr.y*ur.y)
  #define UPD(R,P,cq,cr) { cacc[R] += P; \
      acc[R][0] += P*cq.x; acc[R][1] += P*cq.y; acc[R][2] += P*cq.z; \
      acc[R][3] += P*cq.w; acc[R][4] += P*cr.x; acc[R][5] += P*cr.y; }
  #define SW(RQ,P,cq,cr) switch (RQ){ \
      case 0: UPD(0,P,cq,cr); break; case 1: UPD(1,P,cq,cr); break; \
      case 2: UPD(2,P,cq,cr); break; case 3: UPD(3,P,cq,cr); break; \
      case 4: UPD(4,P,cq,cr); break; case 5: UPD(5,P,cq,cr); break; \
      case 6: UPD(6,P,cq,cr); break; case 7: UPD(7,P,cq,cr); break; \
      default: UPD(8,P,cq,cr); break; }
  for (int p=e0; p<e1; p+=4){
    const f32x4 aq=Aq, bq=Bq, cq=Cq, dq=Dq;
    const f32x2 ar=Ar, br=Br, cr=Cr, dr=Dr;
    const u32 qa=qA, qb=qB, qc=qC, qd=qD;
    const bool h1 = p+1<e1, h2 = p+2<e1, h3 = p+3<e1;
    LDE(A,qA,p+4) LDE(B,qB,p+5) LDE(C,qC,p+6) LDE(D,qD,p+7)
    float pa = DOT(aq,ar), pb = DOT(bq,br);
    float pc = DOT(cq,cr), pd = DOT(dq,dr);
    // 16-lane rotate-reduce via DPP (VALU), then xor16 (swizzle), xor32 (shfl)
    pa += dppror<1>(pa); pb += dppror<1>(pb); pc += dppror<1>(pc); pd += dppror<1>(pd);
    pa += dppror<2>(pa); pb += dppror<2>(pb); pc += dppror<2>(pc); pd += dppror<2>(pd);
    pa += dppror<4>(pa); pb += dppror<4>(pb); pc += dppror<4>(pc); pd += dppror<4>(pd);
    pa += dppror<8>(pa); pb += dppror<8>(pb); pc += dppror<8>(pc); pd += dppror<8>(pd);
    pa += swz16(pa); pb += swz16(pb); pc += swz16(pc); pd += swz16(pd);
    pa += __shfl_xor(pa,32); pb += __shfl_xor(pb,32);
    pc += __shfl_xor(pc,32); pd += __shfl_xor(pd,32);
    SW(qa>>28, pa, aq,ar);
    if (h1){ SW(qb>>28, pb, bq,br); }
    if (h2){ SW(qc>>28, pc, cq,cr); }
    if (h3){ SW(qd>>28, pd, dq,dr); }
  }
  #undef LDE
  #undef DOT
  #undef UPD
  #undef SW
  u16* srow = s + (long)i*KS;
  #pragma unroll
  for (int r=0;r<RR;r++){
    const float inv = 1.0f / nc[r];
    const u32 pk0 = pkbf(acc[r][0]*inv, acc[r][1]*inv);
    const u32 pk1 = pkbf(acc[r][2]*inv, acc[r][3]*inv);
    const u32 pk2 = pkbf(acc[r][4]*inv, acc[r][5]*inv);
    *(u32x2*)(srow + r*DIN + 4*l) = (u32x2){pk0, pk1};   // cols 4l..4l+3
    ((u32*)(srow + r*DIN + 256))[l] = pk2;               // cols 256+{2l,2l+1}
  }
  float cv = 0.f;
  #pragma unroll
  for (int r=0;r<RR;r++) cv = (l == r) ? cacc[r] : cv;
  if (l < 32){
    const float invl = (l < RR) ? 1.0f/nc[l] : 0.f;
    srow[KSU + l] = f2bf(l < RR ? cv*invl : 0.f);
  }
}

// ---------------- 256x256 deep-pipelined bf16 GEMM: C = A * B^T (K-major) -----
// 512 threads = 8 waves (2 wm x 4 wn), per-wave C = 128x64.
// BK=32; 4-slot LDS ring (128 KiB), prefetch distance 3; ONE raw s_barrier +
// ONE counted s_waitcnt vmcnt per K-tile (8 loads = 2 tiles stay in flight
// across every barrier — T3+T4). K-slot XOR swizzle slot^=(row>>1)&3 applied
// via inverse-swizzled GLOBAL source (gll16 dest linear) + swizzled ds_read
// (T2: frag reads 2-way instead of 8-way). setprio around MFMA cluster (T5).
// Race-freedom: STAGE(t+3) writes slot (t-1)&3, whose readers all finished
// before the barrier that ended tile t-1 (ds_reads complete before MFMA).
// 1-D grid with bijective XCD-chunk swizzle (nwg%8==0, cpx%NT==0).
// MODE 0: O0 = relu(C) bf16 (gemm1) ; MODE 1: n<768 -> O0=C+b0 else O1=C+b1
template<int MODE, int NT>
__global__ __launch_bounds__(512, 2)
void k_gemm256(const u16* __restrict__ A, const u16* __restrict__ B, int K,
               u16* __restrict__ O0, u16* __restrict__ O1,
               const float* __restrict__ b0, const float* __restrict__ b1)
{
  __shared__ __align__(16) u16 lds[4][2][256*32];   // 128 KiB: [slot][A|B][row*32+k]
  const int cpx = gridDim.x >> 3;
  const int bid = blockIdx.x;
  const int lg  = (bid & 7)*cpx + (bid >> 3);
  const int mt  = lg / NT;
  const long m0 = (long)mt * 256;
  const long n0 = (long)(lg - mt*NT) * 256;
  const int t   = threadIdx.x;
  const int wv  = t >> 6;
  const int ln  = t & 63;
  const int wm  = wv >> 2;          // 0..1
  const int wn  = wv & 3;           // 0..3
  const int fr  = ln & 15, fq = ln >> 4;

  // staging: thread t covers row lrow of a 128-row chunk, LDS slot_l = t&3 (linear);
  // global k-slot it must fetch = (t&3) ^ ((lrow>>1)&3)  (inverse swizzle)
  const int lrow  = t >> 2;
  const int gslot = (t & 3) ^ ((lrow >> 1) & 3);

  f32x4 acc[8][4];
  #pragma unroll
  for (int i=0;i<8;i++)
    #pragma unroll
    for (int j=0;j<4;j++) acc[i][j] = {0.f,0.f,0.f,0.f};

  const int nk = K >> 5;

  #define STAGE(TT) { const int tt_ = (TT); const long k0_ = (long)tt_*32;          \
    u16* sa_ = &lds[tt_ & 3][0][0]; u16* sb_ = &lds[tt_ & 3][1][0];                 \
    gll16(A + (m0 +       lrow)*(long)K + k0_ + gslot*8, sa_ + wv*512);             \
    gll16(A + (m0 + 128 + lrow)*(long)K + k0_ + gslot*8, sa_ + 4096 + wv*512);      \
    gll16(B + (n0 +       lrow)*(long)K + k0_ + gslot*8, sb_ + wv*512);             \
    gll16(B + (n0 + 128 + lrow)*(long)K + k0_ + gslot*8, sb_ + 4096 + wv*512); }

  STAGE(0) STAGE(1) STAGE(2)
  asm volatile("s_waitcnt vmcnt(8)" ::: "memory");   // tile 0 landed; 1,2 in flight
  __builtin_amdgcn_s_barrier();

  for (int tt = 0; tt < nk; ++tt){
    if (tt + 3 < nk) STAGE(tt + 3)
    const u16* sa = &lds[tt & 3][0][0];
    const u16* sb = &lds[tt & 3][1][0];
    b16x8 av[8], bv[4];
    #pragma unroll
    for (int i=0;i<8;i++){
      const int row = wm*128 + i*16 + fr;
      av[i] = *(const b16x8*)((const u8*)sa + row*64 + ((fq ^ ((row>>1)&3)) << 4));
    }
    #pragma unroll
    for (int j=0;j<4;j++){
      const int row = wn*64 + j*16 + fr;
      bv[j] = *(const b16x8*)((const u8*)sb + row*64 + ((fq ^ ((row>>1)&3)) << 4));
    }
    __builtin_amdgcn_s_setprio(1);
    #pragma unroll
    for (int i=0;i<8;i++)
      #pragma unroll
      for (int j=0;j<4;j++)
        acc[i][j] = __builtin_amdgcn_mfma_f32_16x16x32_bf16(av[i], bv[j], acc[i][j], 0, 0, 0);
    __builtin_amdgcn_s_setprio(0);
    if (tt + 3 < nk)      asm volatile("s_waitcnt vmcnt(8)" ::: "memory");
    else if (tt + 2 < nk) asm volatile("s_waitcnt vmcnt(4)" ::: "memory");
    else if (tt + 1 < nk) asm volatile("s_waitcnt vmcnt(0)" ::: "memory");
    __builtin_amdgcn_s_barrier();
  }
  #undef STAGE

  #pragma unroll
  for (int i=0;i<8;i++){
    #pragma unroll
    for (int j=0;j<4;j++){
      #pragma unroll
      for (int r=0;r<4;r++){
        const long m = m0 + wm*128 + i*16 + fq*4 + r;   // C row = quad*4+reg
        const long n = n0 + wn*64  + j*16 + fr;         // C col = lane&15
        float v = acc[i][j][r];
        if (MODE == 0){
          v = v > 0.f ? v : 0.f;
          O0[m*DH + n] = f2bf(v);
        } else {
          if (n < DH) O0[m*DH + n]      = f2bf(v + b0[n]);
          else        O1[m*DH + (n-DH)] = f2bf(v + b1[n-DH]);
        }
      }
    }
  }
}

// ---------------- phase2 fused with mean-pool: aggr2 + self + relu -> pooled ----
__global__ __launch_bounds__(128) void k_phase2(const u16* __restrict__ hm,
                                                const u16* __restrict__ sfx,
                                                const int* __restrict__ sp,
                                                const int* __restrict__ starts,
                                                float* __restrict__ pooledP){
  const int t  = threadIdx.x;
  const int i0 = blockIdx.x * NPB;
  const int p0 = starts[i0];
  const int pend = starts[i0 + NPB];
  u32 sf00,sf01,sf02, sf10,sf11,sf12, sf20,sf21,sf22, sf30,sf31,sf32;
  { const u32* sr = (const u32*)(sfx + (long)(i0+0)*DH); sf00=sr[t]; sf01=sr[t+128]; sf02=sr[t+256]; }
  { const u32* sr = (const u32*)(sfx + (long)(i0+1)*DH); sf10=sr[t]; sf11=sr[t+128]; sf12=sr[t+256]; }
  { const u32* sr = (const u32*)(sfx + (long)(i0+2)*DH); sf20=sr[t]; sf21=sr[t+128]; sf22=sr[t+256]; }
  { const u32* sr = (const u32*)(sfx + (long)(i0+3)*DH); sf30=sr[t]; sf31=sr[t+128]; sf32=sr[t+256]; }
  u32 A0=0,A1=0,A2=0,B0=0,B1=0,B2=0,C0=0,C1=0,C2=0,D0=0,D1=0,D2=0;
  u32 E0=0,E1=0,E2=0,F0=0,F1=0,F2=0,G0=0,G1=0,G2=0,H0=0,H1=0,H2=0;
  #define PLD(S, IDX) { const int nf_=(IDX); if (nf_ < pend){ \
      const u32* hr_ = (const u32*)(hm + (long)(((u32)sp[nf_]) & 0x3FFFu)*DH); \
      S##0=hr_[t]; S##1=hr_[t+128]; S##2=hr_[t+256]; } }
  PLD(A,p0)   PLD(B,p0+1) PLD(C,p0+2) PLD(D,p0+3)
  PLD(E,p0+4) PLD(F,p0+5) PLD(G,p0+6) PLD(H,p0+7)
  float a0=0.f,a1=0.f,a2=0.f,a3=0.f,a4=0.f,a5=0.f;
  float q0=0.f,q1=0.f,q2=0.f,q3=0.f,q4=0.f,q5=0.f;
  int i = i0;
  int e1 = starts[i0+1];
  #define FLUSH(K) { float v_; \
    v_=a0+bf2f((u16)sf##K##0);        q0+=fmaxf(v_,0.f); \
    v_=a1+bf2f((u16)(sf##K##0>>16));  q1+=fmaxf(v_,0.f); \
    v_=a2+bf2f((u16)sf##K##1);        q2+=fmaxf(v_,0.f); \
    v_=a3+bf2f((u16)(sf##K##1>>16));  q3+=fmaxf(v_,0.f); \
    v_=a4+bf2f((u16)sf##K##2);        q4+=fmaxf(v_,0.f); \
    v_=a5+bf2f((u16)(sf##K##2>>16));  q5+=fmaxf(v_,0.f); \
    a0=a1=a2=a3=a4=a5=0.f; }
  #define FLUSHI { switch (i - i0){ case 0: FLUSH(0); break; case 1: FLUSH(1); break; \
                   case 2: FLUSH(2); break; default: FLUSH(3); break; } }
  while (i < i0+NPB && e1 == p0){ FLUSHI; ++i; e1 = (i < i0+NPB) ? starts[i+1] : 0x7fffffff; }
  #define STEP(S, K) { const int pe_ = base + K; if (pe_ < pend){ \
      const u32 d0_=S##0, d1_=S##1, d2_=S##2; \
      PLD(S, pe_ + 8); \
      a0+=bf2f((u16)d0_); a1+=bf2f((u16)(d0_>>16)); \
      a2+=bf2f((u16)d1_); a3+=bf2f((u16)(d1_>>16)); \
      a4+=bf2f((u16)d2_); a5+=bf2f((u16)(d2_>>16)); \
      while (i < i0+NPB && pe_+1 == e1){ FLUSHI; ++i; \
        e1 = (i < i0+NPB) ? starts[i+1] : 0x7fffffff; } } }
  for (int base = p0; base < pend; base += 8){
    STEP(A,0) STEP(B,1) STEP(C,2) STEP(D,3)
    STEP(E,4) STEP(F,5) STEP(G,6) STEP(H,7)
  }
  while (i < i0+NPB){ FLUSHI; ++i; }
  #undef PLD
  #undef FLUSH
  #undef FLUSHI
  #undef STEP
  float* pd = pooledP + (blockIdx.x & (PCOP-1)) * DH;
  atomicAdd(&pd[2*t],       q0);
  atomicAdd(&pd[2*t+1],     q1);
  atomicAdd(&pd[256+2*t],   q2);
  atomicAdd(&pd[256+2*t+1], q3);
  atomicAdd(&pd[512+2*t],   q4);
  atomicAdd(&pd[512+2*t+1], q5);
}

__global__ __launch_bounds__(256) void k_final(const float* __restrict__ pooledP,
                                               const float* __restrict__ oW,
                                               const float* __restrict__ ob,
                                               float* __restrict__ out){
  __shared__ float ps[DH];
  __shared__ float red[256];
  const int t = threadIdx.x;
  for (int h=t; h<DH; h+=256){
    float s = 0.f;
    #pragma unroll
    for (int c=0;c<PCOP;c++) s += pooledP[c*DH + h];
    ps[h] = s;
  }
  __syncthreads();
  for (int c=0;c<5;c++){
    float p = 0.f;
    for (int h=t; h<DH; h+=256) p += ps[h]*oW[c*DH + h];
    red[t] = p; __syncthreads();
    for (int o=128;o;o>>=1){ if (t<o) red[t]+=red[t+o]; __syncthreads(); }
    if (t == 0) out[c] = red[0]*(1.f/(float)NN) + ob[c];
    __syncthreads();
  }
}

// ---------------- launch ----------------
extern "C" void kernel_launch(void* const* d_in, const int* in_sizes, int n_in,
                              void* d_out, int out_size, void* d_ws, size_t ws_size,
                              hipStream_t stream)
{
  (void)in_sizes; (void)n_in; (void)out_size; (void)ws_size;
  const float* x     = (const float*)d_in[0];
  const int*   ei    = (const int*)  d_in[1];   // [2][E]: row0=src, row1=dst
  const int*   et    = (const int*)  d_in[2];
  const float* relW  = (const float*)d_in[3];
  const float* relb  = (const float*)d_in[4];
  const float* nc    = (const float*)d_in[5];
  const float* linW  = (const float*)d_in[6];
  const float* linb  = (const float*)d_in[7];
  const float* selfW = (const float*)d_in[8];
  const float* selfb = (const float*)d_in[9];
  const float* outW  = (const float*)d_in[10];
  const float* outb  = (const float*)d_in[11];
  float* out = (float*)d_out;

  // workspace layout (256B aligned); hm/selfx alias S (dead after gemm1)
  u8* w = (u8*)d_ws;
  int*   counts = (int*)(w + 0);              // 64 KB
  int*   starts = (int*)(w + 65536);          // 16385*4
  int*   cursor = (int*)(w + 131328);         // 64 KB
  int*   srcp   = (int*)(w + 196864);         // 1 MB (packed src|rel<<28)
  u16*   Wst    = (u16*)(w + 4391168);        // 768*3488*2  = 5.36 MB
  u16*   WB     = (u16*)(w + 9748736);        // 1536*768*2  = 2.36 MB
  u16*   x1     = (u16*)(w + 12108032);       // 16384*768*2 = 25.2 MB
  u16*   S      = (u16*)(w + 37276928);       // 16384*3488*2 = 114.3 MB
  u16*   hm     = S;                          // alias: 25.2 MB
  u16*   sfx    = (u16*)(w + 37276928 + 25165824);
  // partial pooled copies live in S's tail (dead after gemm1 reads S)
  float* pooledP = (float*)(w + 37276928 + 50331648);  // PCOP*768*4 = 48 KB

  const int* esrc = ei;
  const int* edst = ei + EE;

  hipMemsetAsync(counts, 0, NN*sizeof(int), stream);

  k_count <<<EE/256, 256, 0, stream>>>(edst, counts);
  k_scan  <<<1, 1024, 0, stream>>>(counts, starts, cursor);
  k_place <<<EE/256, 256, 0, stream>>>(esrc, edst, et, cursor, srcp);
  k_convW1<<<dim3(14, DH), 256, 0, stream>>>(relW, relb, Wst);
  k_convW2<<<(2*DH*DH)/256, 256, 0, stream>>>(linW, selfW, WB);
  k_phase1f<<<NN/4, 256, 0, stream>>>(x, srcp, nc, starts, S);
  k_gemm256<0,3><<<(NN/256)*(DH/256), 512, 0, stream>>>(
      S, Wst, KS, x1, (u16*)nullptr, (const float*)nullptr, (const float*)nullptr);
  // S fully consumed by gemm1; its tail is now free for the pooled partials
  hipMemsetAsync(pooledP, 0, PCOP*DH*sizeof(float), stream);
  k_gemm256<1,6><<<(NN/256)*(2*DH/256), 512, 0, stream>>>(
      x1, WB, DH, hm, sfx, linb, selfb);
  k_phase2<<<NN/NPB, 128, 0, stream>>>(hm, sfx, srcp, starts, pooledP);
  k_final <<<1, 256, 0, stream>>>(pooledP, outW, outb, out);
}